// Round 4
// baseline (552.140 us; speedup 1.0000x reference)
//
#include <hip/hip_runtime.h>
#include <hip/hip_bf16.h>
#include <stdint.h>

#define B_   128
#define N_   196
#define E_   2048
#define D_   512
#define A_   512
#define MTOT (B_ * N_)   // 25088 = 196*128 exactly

typedef short  short8  __attribute__((ext_vector_type(8)));
typedef float  floatx4 __attribute__((ext_vector_type(4)));

__device__ __forceinline__ unsigned short f2bf(float f) {
    union { float f; uint32_t u; } v; v.f = f;
    uint32_t r = v.u + 0x7FFFu + ((v.u >> 16) & 1u);   // RNE
    return (unsigned short)(r >> 16);
}

// pack two fp32 -> two bf16 (round-half-up) in one dword: lo=bf16(a), hi=bf16(b)
__device__ __forceinline__ uint32_t pkbf(float a, float b) {
    uint32_t ua = __float_as_uint(a) + 0x8000u;
    uint32_t ub = __float_as_uint(b) + 0x8000u;
    return __builtin_amdgcn_perm(ub, ua, 0x07060302u);
}

// ---------------------------------------------------------------------------
// Kernel A2: We [2048][512] fp32 -> WeT [512][2048] bf16 (k-contiguous rows)
// ---------------------------------------------------------------------------
__global__ void transcvt_k(const float* __restrict__ We, unsigned short* __restrict__ WeT) {
    __shared__ float tile[32][33];
    const int e0 = blockIdx.x * 32, a0 = blockIdx.y * 32;
    const int t = threadIdx.x, tc = t & 31, tr = t >> 5;   // tr 0..7
#pragma unroll
    for (int i = 0; i < 4; ++i) {
        int r = tr + i * 8;
        tile[r][tc] = We[(size_t)(e0 + r) * A_ + a0 + tc];
    }
    __syncthreads();
#pragma unroll
    for (int i = 0; i < 4; ++i) {
        int r = tr + i * 8;
        WeT[(size_t)(a0 + r) * E_ + e0 + tc] = f2bf(tile[tc][r]);
    }
}

// ---------------------------------------------------------------------------
// Kernel A: att2p[b][a] = dh[b,:]@Wd[:,a] + bd[a] + be[a]   (fp32, tiny)
// ---------------------------------------------------------------------------
__launch_bounds__(512)
__global__ void att2_k(const float* __restrict__ dh, const float* __restrict__ Wd,
                       const float* __restrict__ bd, const float* __restrict__ be,
                       float* __restrict__ att2p) {
    const int b = blockIdx.x, t = threadIdx.x;
    __shared__ float sdh[D_];
    sdh[t] = dh[b * D_ + t];
    __syncthreads();
    float acc = 0.f;
#pragma unroll 8
    for (int d = 0; d < D_; ++d) acc += sdh[d] * Wd[(size_t)d * A_ + t];
    att2p[(size_t)b * A_ + t] = acc + bd[t] + be[t];
}

// ---------------------------------------------------------------------------
// Kernel B v5: m97-geometry MFMA GEMM + tanh + Wf-dot epilogue.
//   Round-3 diagnosis: NOT occupancy (r2), NOT L2 BW (~0.9 TB/s/XCD) -- the
//   A reg-staging chain is latency-exposed: __syncthreads drains vmcnt(0)
//   every iter, capping the A load->use window at one compute phase.
//   v5 = T4 counted vmcnt: raw s_barrier + "lgkmcnt(0) vmcnt(4)".
//   Issue order pinned (sched_barrier): B(k+1) global_load_lds FIRST (2,
//   oldest), A(k+2) reg loads SECOND (4, newer). vmcnt(4) => B complete,
//   A(k+2) stays in flight ACROSS the barrier -> A window ~2 iterations.
//   Register rotation via static names rA*/rB*, manual 2x unroll (rule #20).
// ---------------------------------------------------------------------------
__launch_bounds__(256, 4)
__global__ void score_gemm(const float* __restrict__ enc,
                           const unsigned short* __restrict__ WeT,
                           const float* __restrict__ att2p,
                           const float* __restrict__ Wf,
                           float* __restrict__ scoresP) {
    // per buffer (16 KB): A 128r x 32k bf16 (64B/row, 8KB) @0 ; B 128 x 32k bf16 @8192
    __shared__ __align__(16) char sMem[2 * 16384];   // 32 KB double buffer
    __shared__ float sPart[2][128];

    const int t   = threadIdx.x;
    const int w   = t >> 6;               // 0..3
    const int l   = t & 63;
    const int l15 = l & 15;
    const int q4  = l >> 4;
    const int wr  = w >> 1, wc = w & 1;   // 2x2 wave grid

    // bijective XCD swizzle (784 = 8*98): strip's 4 col-blocks -> same XCD
    const int v     = (blockIdx.x & 7) * 98 + (blockIdx.x >> 3);
    const int strip = v >> 2, colb = v & 3;
    const int row0  = strip * 128;
    const int c0    = colb * 128;

    floatx4 acc[4][4] = {};

    // ---- A staging (reg-staged fp32->bf16): thread -> row ar=t>>1, half ah=t&1
    const int ar = t >> 1, ah = t & 1;
    const float* aSrcT = enc + (size_t)(row0 + ar) * E_ + ah * 16;
    const int aswz = (ar >> 1) & 3;
    const int aWr0 = ar * 64 + (((2 * ah)     ^ aswz) * 16);
    const int aWr1 = ar * 64 + (((2 * ah + 1) ^ aswz) * 16);

    // ---- B DMA: 8 wave-insts (2/wave). slot s=w*2+j -> n=s*16+(l>>2), chunk p=l&3
    const unsigned short* bSrc[2];
    int bDst[2];
#pragma unroll
    for (int j = 0; j < 2; ++j) {
        int s = w * 2 + j;
        int n = s * 16 + (l >> 2), p = l & 3;
        int q = p ^ ((n >> 1) & 3);
        bSrc[j] = WeT + (size_t)(c0 + n) * E_ + q * 8;
        bDst[j] = 8192 + s * 1024;        // wave-uniform base; dest linear in lane
    }

    // ---- LDS read offsets (within one buffer); phys chunk = q4 ^ ((row>>1)&3)
    const int chR  = q4 ^ ((l15 >> 1) & 3);
    const int offA = (wr * 64 + l15) * 64 + chR * 16;          // + mi*1024
    const int offB = 8192 + (wc * 64 + l15) * 64 + chR * 16;   // + ni*1024

    float4 rA0, rA1, rA2, rA3, rB0, rB1, rB2, rB3;

    // ---- prologue: stage tile 0 into buf0; preload A(1) into rA
    {
#pragma unroll
        for (int j = 0; j < 2; ++j)
            __builtin_amdgcn_global_load_lds(
                (const __attribute__((address_space(1))) uint32_t*)(bSrc[j]),
                (__attribute__((address_space(3))) uint32_t*)(sMem + bDst[j]), 16, 0, 0);
        float4 p0 = *(const float4*)(aSrcT);
        float4 p1 = *(const float4*)(aSrcT + 4);
        float4 p2 = *(const float4*)(aSrcT + 8);
        float4 p3 = *(const float4*)(aSrcT + 12);
        rA0 = *(const float4*)(aSrcT + 32);
        rA1 = *(const float4*)(aSrcT + 36);
        rA2 = *(const float4*)(aSrcT + 40);
        rA3 = *(const float4*)(aSrcT + 44);
        uint4 w0, w1;
        w0.x = pkbf(p0.x, p0.y); w0.y = pkbf(p0.z, p0.w);
        w0.z = pkbf(p1.x, p1.y); w0.w = pkbf(p1.z, p1.w);
        w1.x = pkbf(p2.x, p2.y); w1.y = pkbf(p2.z, p2.w);
        w1.z = pkbf(p3.x, p3.y); w1.w = pkbf(p3.z, p3.w);
        *(uint4*)(sMem + aWr0) = w0;
        *(uint4*)(sMem + aWr1) = w1;
        __syncthreads();                  // full drain once at startup
    }

    // KSTEP(CUR,NXT): compute tile KK from CUR; stage B(KK+1)->NXT (issued
    // first, oldest), A(KK+2)->RN* (newer); write RO*=A(KK+1)->NXT;
    // barrier with vmcnt(4): B done, A(KK+2) still in flight.
#define KSTEP(CUROFF, NXTOFF, RO0, RO1, RO2, RO3, RN0, RN1, RN2, RN3, KK)        \
    {                                                                             \
        const int kn1 = ((KK) + 1) & 63;                                          \
        const int kn2 = ((KK) + 2) & 63;                                          \
        _Pragma("unroll")                                                         \
        for (int j = 0; j < 2; ++j)                                               \
            __builtin_amdgcn_global_load_lds(                                     \
                (const __attribute__((address_space(1))) uint32_t*)(bSrc[j] + kn1 * 32), \
                (__attribute__((address_space(3))) uint32_t*)(sMem + (NXTOFF) + bDst[j]), 16, 0, 0); \
        __builtin_amdgcn_sched_barrier(0);                                        \
        RN0 = *(const float4*)(aSrcT + kn2 * 32);                                 \
        RN1 = *(const float4*)(aSrcT + kn2 * 32 + 4);                             \
        RN2 = *(const float4*)(aSrcT + kn2 * 32 + 8);                             \
        RN3 = *(const float4*)(aSrcT + kn2 * 32 + 12);                            \
        __builtin_amdgcn_sched_barrier(0);                                        \
        short8 bfr[4];                                                            \
        _Pragma("unroll")                                                         \
        for (int ni = 0; ni < 4; ++ni)                                            \
            bfr[ni] = *(const short8*)(sMem + (CUROFF) + offB + ni * 1024);       \
        _Pragma("unroll")                                                         \
        for (int mi = 0; mi < 4; ++mi) {                                          \
            short8 a = *(const short8*)(sMem + (CUROFF) + offA + mi * 1024);      \
            acc[mi][0] = __builtin_amdgcn_mfma_f32_16x16x32_bf16(a, bfr[0], acc[mi][0], 0, 0, 0); \
            acc[mi][1] = __builtin_amdgcn_mfma_f32_16x16x32_bf16(a, bfr[1], acc[mi][1], 0, 0, 0); \
            acc[mi][2] = __builtin_amdgcn_mfma_f32_16x16x32_bf16(a, bfr[2], acc[mi][2], 0, 0, 0); \
            acc[mi][3] = __builtin_amdgcn_mfma_f32_16x16x32_bf16(a, bfr[3], acc[mi][3], 0, 0, 0); \
        }                                                                         \
        {                                                                         \
            uint4 w0, w1;                                                         \
            w0.x = pkbf(RO0.x, RO0.y); w0.y = pkbf(RO0.z, RO0.w);                 \
            w0.z = pkbf(RO1.x, RO1.y); w0.w = pkbf(RO1.z, RO1.w);                 \
            w1.x = pkbf(RO2.x, RO2.y); w1.y = pkbf(RO2.z, RO2.w);                 \
            w1.z = pkbf(RO3.x, RO3.y); w1.w = pkbf(RO3.z, RO3.w);                 \
            *(uint4*)(sMem + (NXTOFF) + aWr0) = w0;                               \
            *(uint4*)(sMem + (NXTOFF) + aWr1) = w1;                               \
        }                                                                         \
        asm volatile("s_waitcnt lgkmcnt(0) vmcnt(4)" ::: "memory");               \
        __builtin_amdgcn_s_barrier();                                             \
    }

    for (int kk = 0; kk < 64; kk += 2) {
        KSTEP(0,     16384, rA0, rA1, rA2, rA3, rB0, rB1, rB2, rB3, kk);
        KSTEP(16384, 0,     rB0, rB1, rB2, rB3, rA0, rA1, rA2, rA3, kk + 1);
    }
#undef KSTEP

    // ---- Epilogue: partial score over this block's 128 cols
    const int cbase = c0 + wc * 64;
    float wfv[4];
#pragma unroll
    for (int ni = 0; ni < 4; ++ni) wfv[ni] = Wf[cbase + ni * 16 + l15];

#pragma unroll
    for (int mi = 0; mi < 4; ++mi) {
#pragma unroll
        for (int r = 0; r < 4; ++r) {
            const int m    = wr * 64 + mi * 16 + q4 * 4 + r;   // row within block
            const int grow = row0 + m;
            const int bb   = grow / N_;
            const float* a2p = att2p + (size_t)bb * A_ + cbase;
            float s = 0.f;
#pragma unroll
            for (int ni = 0; ni < 4; ++ni) {
                float vv = acc[mi][ni][r] + a2p[ni * 16 + l15];
                float e  = __expf(2.f * vv);
                float th = 1.f - 2.f / (e + 1.f);      // tanh(vv)
                s += th * wfv[ni];
            }
            s += __shfl_xor(s, 1);
            s += __shfl_xor(s, 2);
            s += __shfl_xor(s, 4);
            s += __shfl_xor(s, 8);
            if (l15 == 0) sPart[wc][m] = s;
        }
    }
    __syncthreads();
    if (t < 128) {
        scoresP[(size_t)colb * MTOT + row0 + t] = sPart[0][t] + sPart[1][t];
    }
}

// ---------------------------------------------------------------------------
// Kernel C: fused softmax + context.
// Each block (chunk, b) recomputes the tiny softmax for batch b from the FOUR
// score partials, then accumulates its 256-float E-chunk of context.
// ---------------------------------------------------------------------------
__launch_bounds__(256)
__global__ void ctx_sm_k(const float* __restrict__ enc, const float* __restrict__ sp,
                         float* __restrict__ alpha, float* __restrict__ ctx) {
    const int chunk = blockIdx.x, b = blockIdx.y;
    const int t = threadIdx.x, w = t >> 6, l = t & 63;
    const int tn = t >> 6, tc = t & 63;
    __shared__ float  sAl[N_];
    __shared__ float  red[8];
    __shared__ float4 sRed[256];

    float v = -3.0e38f;
    if (t < N_) {
        const int i = b * N_ + t;
        v = sp[i] + sp[MTOT + i] + sp[2 * MTOT + i] + sp[3 * MTOT + i];
    }
    float m = v;
#pragma unroll
    for (int off = 32; off >= 1; off >>= 1) m = fmaxf(m, __shfl_xor(m, off));
    if (l == 0) red[w] = m;
    __syncthreads();
    m = fmaxf(fmaxf(red[0], red[1]), fmaxf(red[2], red[3]));
    float e = 0.f;
    if (t < N_) e = __expf(v - m);
    float s = e;
#pragma unroll
    for (int off = 32; off >= 1; off >>= 1) s += __shfl_xor(s, off);
    if (l == 0) red[4 + w] = s;
    __syncthreads();
    s = red[4] + red[5] + red[6] + red[7];
    if (t < N_) {
        float al = e / s;
        sAl[t] = al;
        if (chunk == 0) alpha[b * N_ + t] = al;
    }
    __syncthreads();

    const float* base = enc + (size_t)b * N_ * E_ + chunk * 256 + tc * 4;
    float4 a = make_float4(0.f, 0.f, 0.f, 0.f);
#pragma unroll 7
    for (int n = tn; n < N_; n += 4) {
        float  al = sAl[n];
        float4 vv = *(const float4*)(base + (size_t)n * E_);
        a.x += al * vv.x; a.y += al * vv.y; a.z += al * vv.z; a.w += al * vv.w;
    }
    sRed[t] = a;
    __syncthreads();
    if (t < 64) {
        float4 r0 = sRed[t], r1 = sRed[t + 64], r2 = sRed[t + 128], r3 = sRed[t + 192];
        float4 o = make_float4(r0.x + r1.x + r2.x + r3.x, r0.y + r1.y + r2.y + r3.y,
                               r0.z + r1.z + r2.z + r3.z, r0.w + r1.w + r2.w + r3.w);
        *(float4*)(ctx + (size_t)b * E_ + chunk * 256 + t * 4) = o;
    }
}

// ---------------------------------------------------------------------------
extern "C" void kernel_launch(void* const* d_in, const int* in_sizes, int n_in,
                              void* d_out, int out_size, void* d_ws, size_t ws_size,
                              hipStream_t stream) {
    const float* enc = (const float*)d_in[0];
    const float* dh  = (const float*)d_in[1];
    const float* We  = (const float*)d_in[2];
    const float* be  = (const float*)d_in[3];
    const float* Wd  = (const float*)d_in[4];
    const float* bd  = (const float*)d_in[5];
    const float* Wf  = (const float*)d_in[6];
    // d_in[7] = bf: additive constant on scores, cancels in softmax.

    float* out   = (float*)d_out;
    float* ctx   = out;              // [128, 2048]
    float* alpha = out + B_ * E_;    // [128, 196]

    char* ws = (char*)d_ws;
    unsigned short* WeT  = (unsigned short*)ws;                       // 2 MB
    float* att2p         = (float*)(ws + (2u << 20));                 // 256 KB
    float* scoresP       = (float*)(ws + (2u << 20) + (256u << 10));  // 4 x 25088 fp32

    transcvt_k <<<dim3(E_ / 32, A_ / 32), 256, 0, stream>>>(We, WeT);
    att2_k     <<<dim3(B_),              512, 0, stream>>>(dh, Wd, bd, be, att2p);
    score_gemm <<<dim3(4 * MTOT / 128),  256, 0, stream>>>(enc, WeT, att2p, Wf, scoresP);
    ctx_sm_k   <<<dim3(E_ / 256, B_),    256, 0, stream>>>(enc, scoresP, alpha, ctx);
}

// Round 8
// 430.342 us; speedup vs baseline: 1.2830x; 1.2830x over previous
//
#include <hip/hip_runtime.h>
#include <hip/hip_bf16.h>
#include <stdint.h>

#define B_   128
#define N_   196
#define E_   2048
#define D_   512
#define A_   512
#define MTOT (B_ * N_)   // 25088 = 196*128 exactly

typedef short  short8  __attribute__((ext_vector_type(8)));
typedef float  floatx4 __attribute__((ext_vector_type(4)));

__device__ __forceinline__ unsigned short f2bf(float f) {
    union { float f; uint32_t u; } v; v.f = f;
    uint32_t r = v.u + 0x7FFFu + ((v.u >> 16) & 1u);   // RNE
    return (unsigned short)(r >> 16);
}

// pack two fp32 -> two bf16 (round-half-up) in one dword: lo=bf16(a), hi=bf16(b)
__device__ __forceinline__ uint32_t pkbf(float a, float b) {
    uint32_t ua = __float_as_uint(a) + 0x8000u;
    uint32_t ub = __float_as_uint(b) + 0x8000u;
    return __builtin_amdgcn_perm(ub, ua, 0x07060302u);
}

// ---------------------------------------------------------------------------
// Kernel A2: We [2048][512] fp32 -> WeT [512][2048] bf16 (k-contiguous rows)
// ---------------------------------------------------------------------------
__global__ void transcvt_k(const float* __restrict__ We, unsigned short* __restrict__ WeT) {
    __shared__ float tile[32][33];
    const int e0 = blockIdx.x * 32, a0 = blockIdx.y * 32;
    const int t = threadIdx.x, tc = t & 31, tr = t >> 5;   // tr 0..7
#pragma unroll
    for (int i = 0; i < 4; ++i) {
        int r = tr + i * 8;
        tile[r][tc] = We[(size_t)(e0 + r) * A_ + a0 + tc];
    }
    __syncthreads();
#pragma unroll
    for (int i = 0; i < 4; ++i) {
        int r = tr + i * 8;
        WeT[(size_t)(a0 + r) * E_ + e0 + tc] = f2bf(tile[tc][r]);
    }
}

// ---------------------------------------------------------------------------
// Kernel A: att2p[b][a] = dh[b,:]@Wd[:,a] + bd[a] + be[a]   (fp32, tiny)
// ---------------------------------------------------------------------------
__launch_bounds__(512)
__global__ void att2_k(const float* __restrict__ dh, const float* __restrict__ Wd,
                       const float* __restrict__ bd, const float* __restrict__ be,
                       float* __restrict__ att2p) {
    const int b = blockIdx.x, t = threadIdx.x;
    __shared__ float sdh[D_];
    sdh[t] = dh[b * D_ + t];
    __syncthreads();
    float acc = 0.f;
#pragma unroll 8
    for (int d = 0; d < D_; ++d) acc += sdh[d] * Wd[(size_t)d * A_ + t];
    att2p[(size_t)b * A_ + t] = acc + bd[t] + be[t];
}

// ---------------------------------------------------------------------------
// Kernel B v6b: pure-m97 structure (v6 + the wr*64 A-read fix).
//   v6 bug: offAlo/offAhi lacked the wave-row offset wr*64 (BM=128, 2x2 wave
//   grid) -> waves wr=1 read rows 0..63 instead of 64..127 (absmax 0.103).
//   With row = wr*64 + mi*16 + l15, both 64 and 16 are multiples of 8, so the
//   per-row swizzle factor stays l15&7 -> conflict analysis unchanged.
//   Structure: ALL staging via global_load_lds (A fp32, B bf16), single
//   buffer, 2 barriers/iter, NO register-staging chain (v5's spill source).
//   Latency hiding = multi-block overlap (m97/m114), 4 blocks/CU, LDS 25KB.
//   Grid 784 = 196 strips x 4 col-blocks, XCD swizzle (r3-proven FETCH=112MB).
// ---------------------------------------------------------------------------
__launch_bounds__(256, 4)
__global__ void score_gemm(const float* __restrict__ enc,
                           const unsigned short* __restrict__ WeT,
                           const float* __restrict__ att2p,
                           const float* __restrict__ Wf,
                           float* __restrict__ scoresP) {
    // A fp32 16KB @0 ; B bf16 8KB @16384   (single buffer, 24KB)
    __shared__ __align__(16) char sMem[24576];
    __shared__ float sPart[2][128];

    const int t   = threadIdx.x;
    const int w   = t >> 6;               // 0..3
    const int l   = t & 63;
    const int l15 = l & 15;
    const int q4  = l >> 4;
    const int wr  = w >> 1, wc = w & 1;   // 2x2 wave grid

    // bijective XCD swizzle (784 = 8*98): strip's 4 col-blocks -> same XCD
    const int v     = (blockIdx.x & 7) * 98 + (blockIdx.x >> 3);
    const int strip = v >> 2, colb = v & 3;
    const int row0  = strip * 128;
    const int c0    = colb * 128;

    floatx4 acc[4][4] = {};

    // ---- A DMA: 16 wave-insts (4/wave). slot s=(w*4+j)*64+l -> row=s>>3, pc=s&7
    //      global source pre-swizzled: lc = pc ^ (row&7)
    const float* aSrc[4];
    int aDst[4];
#pragma unroll
    for (int j = 0; j < 4; ++j) {
        int s = (w * 4 + j) * 64 + l;
        int r = s >> 3, pc = s & 7;
        aSrc[j] = enc + (size_t)(row0 + r) * E_ + ((pc ^ (r & 7)) * 4);
        aDst[j] = (w * 4 + j) * 1024;     // wave-uniform byte base
    }

    // ---- B DMA: 8 wave-insts (2/wave). slot s=w*2+j -> n=s*16+(l>>2), chunk p=l&3
    const unsigned short* bSrc[2];
    int bDst[2];
#pragma unroll
    for (int j = 0; j < 2; ++j) {
        int s = w * 2 + j;
        int n = s * 16 + (l >> 2), p = l & 3;
        int q = p ^ ((n >> 1) & 3);
        bSrc[j] = WeT + (size_t)(c0 + n) * E_ + q * 8;
        bDst[j] = 16384 + s * 1024;       // wave-uniform base; dest linear in lane
    }

    // ---- LDS read offsets (A includes the wave-row offset wr*64 -- the v6 fix)
    const int pLo    = (2 * q4) ^ (l15 & 7);
    const int offAlo = (wr * 64 + l15) * 128 + pLo * 16;        // + mi*2048
    const int offAhi = (wr * 64 + l15) * 128 + (pLo ^ 1) * 16;
    const int chB    = q4 ^ ((l15 >> 1) & 3);
    const int offB   = 16384 + (wc * 64 + l15) * 64 + chB * 16; // + ni*1024

#pragma unroll 2
    for (int kk = 0; kk < 64; ++kk) {
        // ---- stage tile kk (pure DMA, no register chain)
#pragma unroll
        for (int j = 0; j < 4; ++j)
            __builtin_amdgcn_global_load_lds(
                (const __attribute__((address_space(1))) uint32_t*)(aSrc[j] + kk * 32),
                (__attribute__((address_space(3))) uint32_t*)(sMem + aDst[j]), 16, 0, 0);
#pragma unroll
        for (int j = 0; j < 2; ++j)
            __builtin_amdgcn_global_load_lds(
                (const __attribute__((address_space(1))) uint32_t*)(bSrc[j] + kk * 32),
                (__attribute__((address_space(3))) uint32_t*)(sMem + bDst[j]), 16, 0, 0);
        __syncthreads();                  // drains vmcnt(0): tile ready

        // ---- compute tile kk
        short8 bfr[4];
        union { uint32_t u[4]; short8 s; } af[4];
#pragma unroll
        for (int ni = 0; ni < 4; ++ni)
            bfr[ni] = *(const short8*)(sMem + offB + ni * 1024);
#pragma unroll
        for (int mi = 0; mi < 4; ++mi) {
            float4 lo = *(const float4*)(sMem + offAlo + mi * 2048);  // k q4*8..+3
            float4 hi = *(const float4*)(sMem + offAhi + mi * 2048);  // k q4*8+4..+7
            af[mi].u[0] = pkbf(lo.x, lo.y);
            af[mi].u[1] = pkbf(lo.z, lo.w);
            af[mi].u[2] = pkbf(hi.x, hi.y);
            af[mi].u[3] = pkbf(hi.z, hi.w);
        }
#pragma unroll
        for (int mi = 0; mi < 4; ++mi) {
            acc[mi][0] = __builtin_amdgcn_mfma_f32_16x16x32_bf16(af[mi].s, bfr[0], acc[mi][0], 0, 0, 0);
            acc[mi][1] = __builtin_amdgcn_mfma_f32_16x16x32_bf16(af[mi].s, bfr[1], acc[mi][1], 0, 0, 0);
            acc[mi][2] = __builtin_amdgcn_mfma_f32_16x16x32_bf16(af[mi].s, bfr[2], acc[mi][2], 0, 0, 0);
            acc[mi][3] = __builtin_amdgcn_mfma_f32_16x16x32_bf16(af[mi].s, bfr[3], acc[mi][3], 0, 0, 0);
        }
        __syncthreads();                  // buffer reuse guard
    }

    // ---- Epilogue: partial score over this block's 128 cols
    const int cbase = c0 + wc * 64;
    float wfv[4];
#pragma unroll
    for (int ni = 0; ni < 4; ++ni) wfv[ni] = Wf[cbase + ni * 16 + l15];

#pragma unroll
    for (int mi = 0; mi < 4; ++mi) {
#pragma unroll
        for (int r = 0; r < 4; ++r) {
            const int m    = wr * 64 + mi * 16 + q4 * 4 + r;   // row within block
            const int grow = row0 + m;
            const int bb   = grow / N_;
            const float* a2p = att2p + (size_t)bb * A_ + cbase;
            float s = 0.f;
#pragma unroll
            for (int ni = 0; ni < 4; ++ni) {
                float vv = acc[mi][ni][r] + a2p[ni * 16 + l15];
                float e  = __expf(2.f * vv);
                float th = 1.f - 2.f / (e + 1.f);      // tanh(vv)
                s += th * wfv[ni];
            }
            s += __shfl_xor(s, 1);
            s += __shfl_xor(s, 2);
            s += __shfl_xor(s, 4);
            s += __shfl_xor(s, 8);
            if (l15 == 0) sPart[wc][m] = s;
        }
    }
    __syncthreads();
    if (t < 128) {
        scoresP[(size_t)colb * MTOT + row0 + t] = sPart[0][t] + sPart[1][t];
    }
}

// ---------------------------------------------------------------------------
// Kernel C: fused softmax + context.
// Each block (chunk, b) recomputes the tiny softmax for batch b from the FOUR
// score partials, then accumulates its 256-float E-chunk of context.
// ---------------------------------------------------------------------------
__launch_bounds__(256)
__global__ void ctx_sm_k(const float* __restrict__ enc, const float* __restrict__ sp,
                         float* __restrict__ alpha, float* __restrict__ ctx) {
    const int chunk = blockIdx.x, b = blockIdx.y;
    const int t = threadIdx.x, w = t >> 6, l = t & 63;
    const int tn = t >> 6, tc = t & 63;
    __shared__ float  sAl[N_];
    __shared__ float  red[8];
    __shared__ float4 sRed[256];

    float v = -3.0e38f;
    if (t < N_) {
        const int i = b * N_ + t;
        v = sp[i] + sp[MTOT + i] + sp[2 * MTOT + i] + sp[3 * MTOT + i];
    }
    float m = v;
#pragma unroll
    for (int off = 32; off >= 1; off >>= 1) m = fmaxf(m, __shfl_xor(m, off));
    if (l == 0) red[w] = m;
    __syncthreads();
    m = fmaxf(fmaxf(red[0], red[1]), fmaxf(red[2], red[3]));
    float e = 0.f;
    if (t < N_) e = __expf(v - m);
    float s = e;
#pragma unroll
    for (int off = 32; off >= 1; off >>= 1) s += __shfl_xor(s, off);
    if (l == 0) red[4 + w] = s;
    __syncthreads();
    s = red[4] + red[5] + red[6] + red[7];
    if (t < N_) {
        float al = e / s;
        sAl[t] = al;
        if (chunk == 0) alpha[b * N_ + t] = al;
    }
    __syncthreads();

    const float* base = enc + (size_t)b * N_ * E_ + chunk * 256 + tc * 4;
    float4 a = make_float4(0.f, 0.f, 0.f, 0.f);
#pragma unroll 7
    for (int n = tn; n < N_; n += 4) {
        float  al = sAl[n];
        float4 vv = *(const float4*)(base + (size_t)n * E_);
        a.x += al * vv.x; a.y += al * vv.y; a.z += al * vv.z; a.w += al * vv.w;
    }
    sRed[t] = a;
    __syncthreads();
    if (t < 64) {
        float4 r0 = sRed[t], r1 = sRed[t + 64], r2 = sRed[t + 128], r3 = sRed[t + 192];
        float4 o = make_float4(r0.x + r1.x + r2.x + r3.x, r0.y + r1.y + r2.y + r3.y,
                               r0.z + r1.z + r2.z + r3.z, r0.w + r1.w + r2.w + r3.w);
        *(float4*)(ctx + (size_t)b * E_ + chunk * 256 + t * 4) = o;
    }
}

// ---------------------------------------------------------------------------
extern "C" void kernel_launch(void* const* d_in, const int* in_sizes, int n_in,
                              void* d_out, int out_size, void* d_ws, size_t ws_size,
                              hipStream_t stream) {
    const float* enc = (const float*)d_in[0];
    const float* dh  = (const float*)d_in[1];
    const float* We  = (const float*)d_in[2];
    const float* be  = (const float*)d_in[3];
    const float* Wd  = (const float*)d_in[4];
    const float* bd  = (const float*)d_in[5];
    const float* Wf  = (const float*)d_in[6];
    // d_in[7] = bf: additive constant on scores, cancels in softmax.

    float* out   = (float*)d_out;
    float* ctx   = out;              // [128, 2048]
    float* alpha = out + B_ * E_;    // [128, 196]

    char* ws = (char*)d_ws;
    unsigned short* WeT  = (unsigned short*)ws;                       // 2 MB
    float* att2p         = (float*)(ws + (2u << 20));                 // 256 KB
    float* scoresP       = (float*)(ws + (2u << 20) + (256u << 10));  // 4 x 25088 fp32

    transcvt_k <<<dim3(E_ / 32, A_ / 32), 256, 0, stream>>>(We, WeT);
    att2_k     <<<dim3(B_),              512, 0, stream>>>(dh, Wd, bd, be, att2p);
    score_gemm <<<dim3(4 * MTOT / 128),  256, 0, stream>>>(enc, WeT, att2p, Wf, scoresP);
    ctx_sm_k   <<<dim3(E_ / 256, B_),    256, 0, stream>>>(enc, scoresP, alpha, ctx);
}